// Round 2
// baseline (3401.183 us; speedup 1.0000x reference)
//
#include <hip/hip_runtime.h>
#include <math.h>

#define S_ 448
#define B_ 64
#define F_ 8
#define D_ 256
#define H_ 8
#define DK_ 32
#define L_ 4
#define PRED_ 96
#define NT_ (S_ * B_)          // 28672 tokens

typedef unsigned short bf16_t;

__device__ __forceinline__ float b2f(bf16_t b) {
  return __uint_as_float(((unsigned)b) << 16);
}
__device__ __forceinline__ bf16_t f2b(float f) {
  unsigned u = __float_as_uint(f);
  u += 0x7fffu + ((u >> 16) & 1u);     // round-to-nearest-even
  return (bf16_t)(u >> 16);
}
// 8 consecutive bf16 (as uint4) -> 8 floats
__device__ __forceinline__ void b8f(uint4 v, float* o) {
  o[0] = __uint_as_float(v.x << 16); o[1] = __uint_as_float(v.x & 0xffff0000u);
  o[2] = __uint_as_float(v.y << 16); o[3] = __uint_as_float(v.y & 0xffff0000u);
  o[4] = __uint_as_float(v.z << 16); o[5] = __uint_as_float(v.z & 0xffff0000u);
  o[6] = __uint_as_float(v.w << 16); o[7] = __uint_as_float(v.w & 0xffff0000u);
}

// ---------------------------------------------------------------- embed
__global__ __launch_bounds__(256) void embed_kernel(
    const float* __restrict__ src, const float* __restrict__ w_in,
    const float* __restrict__ b_in, bf16_t* __restrict__ x) {
  int n = blockIdx.x;          // token = s*B + b
  int d = threadIdx.x;         // 0..255
  const float* srow = src + (size_t)n * F_;
  float acc = b_in[d];
#pragma unroll
  for (int f = 0; f < F_; ++f) acc += srow[f] * w_in[f * D_ + d];
  int s = n / B_;
  int i2 = d & ~1;             // 2*i
  float freq = __expf(-9.210340371976184f * (float)i2 / (float)D_);
  float ang = (float)s * freq;
  float pe = (d & 1) ? cosf(ang) : sinf(ang);
  x[(size_t)n * D_ + d] = f2b(acc + pe);
}

// ------------------------------------------------- GEMM 128x128, 8x8 micro
// Y[M,256](bf16) = A[M,256](bf16) @ W[256,256](f32) + bias, opt relu.
__global__ __launch_bounds__(256) void gemm_kernel(
    const bf16_t* __restrict__ A, const float* __restrict__ W,
    const float* __restrict__ bias, bf16_t* __restrict__ Y, int relu) {
  __shared__ float As[16][128];
  __shared__ float Bs[16][128];
  int m0 = blockIdx.x * 128;
  int n0 = blockIdx.y * 128;
  int tid = threadIdx.x;
  int tx = tid & 15;           // col group
  int ty = tid >> 4;           // row group

  float acc[8][8];
#pragma unroll
  for (int i = 0; i < 8; ++i)
#pragma unroll
    for (int j = 0; j < 8; ++j) acc[i][j] = 0.f;

  int arow = tid >> 1;               // 0..127
  int acol = (tid & 1) * 8;          // 0 or 8
  int brow = tid >> 4;               // 0..15
  int bcol = (tid & 15) * 8;         // 0..120

  for (int k0 = 0; k0 < 256; k0 += 16) {
    // prefetch globals
    uint4 av = *(const uint4*)(A + (size_t)(m0 + arow) * 256 + k0 + acol);
    const float* bp = W + (size_t)(k0 + brow) * 256 + n0 + bcol;
    float4 b0 = *(const float4*)(bp);
    float4 b1 = *(const float4*)(bp + 4);
    float af[8];
    b8f(av, af);
    __syncthreads();
#pragma unroll
    for (int j = 0; j < 8; ++j) As[acol + j][arow] = af[j];
    *(float4*)(&Bs[brow][bcol]) = b0;
    *(float4*)(&Bs[brow][bcol + 4]) = b1;
    __syncthreads();
#pragma unroll
    for (int k = 0; k < 16; ++k) {
      float4 av0 = *(const float4*)(&As[k][ty * 4]);
      float4 av1 = *(const float4*)(&As[k][64 + ty * 4]);
      float4 bv0 = *(const float4*)(&Bs[k][tx * 4]);
      float4 bv1 = *(const float4*)(&Bs[k][64 + tx * 4]);
      float ar[8] = {av0.x, av0.y, av0.z, av0.w, av1.x, av1.y, av1.z, av1.w};
      float br[8] = {bv0.x, bv0.y, bv0.z, bv0.w, bv1.x, bv1.y, bv1.z, bv1.w};
#pragma unroll
      for (int i = 0; i < 8; ++i)
#pragma unroll
        for (int j = 0; j < 8; ++j) acc[i][j] += ar[i] * br[j];
    }
  }
#pragma unroll
  for (int i = 0; i < 8; ++i) {
    int row = m0 + ((i < 4) ? (ty * 4 + i) : (64 + ty * 4 + i - 4));
#pragma unroll
    for (int jj = 0; jj < 2; ++jj) {
      int col = n0 + ((jj == 0) ? (tx * 4) : (64 + tx * 4));
      float o0 = acc[i][jj * 4 + 0] + bias[col + 0];
      float o1 = acc[i][jj * 4 + 1] + bias[col + 1];
      float o2 = acc[i][jj * 4 + 2] + bias[col + 2];
      float o3 = acc[i][jj * 4 + 3] + bias[col + 3];
      if (relu) {
        o0 = fmaxf(o0, 0.f); o1 = fmaxf(o1, 0.f);
        o2 = fmaxf(o2, 0.f); o3 = fmaxf(o3, 0.f);
      }
      ushort4 ov;
      ov.x = f2b(o0); ov.y = f2b(o1); ov.z = f2b(o2); ov.w = f2b(o3);
      *(ushort4*)(Y + (size_t)row * 256 + col) = ov;
    }
  }
}

// ---------------------------------------------------------------- attention
// one block per (b,h); K,V staged in LDS (fp32); ctx written in-place over Q.
#define ROWK_ 36
#define ROWV_ 36
#define ROWP_ 16
// LDS floats: Ks 448*36 + Vs 448*36 + Pq 448*16 = 39424  (157,696 B)
__global__ __launch_bounds__(256, 1) void attn_kernel(
    bf16_t* __restrict__ Q, const bf16_t* __restrict__ K,
    const bf16_t* __restrict__ V) {
  extern __shared__ float lds[];
  float* Ks = lds;                          // [448][36]
  float* Vs = Ks + S_ * ROWK_;              // [448][36]
  float* Pq = Vs + S_ * ROWV_;              // [448][16]  (+ reduction scratch)

  int bh = blockIdx.x;
  int b = bh >> 3;
  int h = bh & 7;
  int tid = threadIdx.x;
  int lane = tid & 63;
  int wave = tid >> 6;
  int colbase = h * DK_;

  // stage K,V (8 bf16 per uint4 load, converted to fp32 in LDS)
  for (int i = tid; i < S_ * 4; i += 256) {
    int t = i >> 2, e = i & 3;
    size_t gg = ((size_t)t * B_ + b) * D_ + colbase + e * 8;
    float kf[8], vf[8];
    b8f(*(const uint4*)(K + gg), kf);
    b8f(*(const uint4*)(V + gg), vf);
    float* kd = Ks + (size_t)t * ROWK_ + e * 8;
    float* vd = Vs + (size_t)t * ROWV_ + e * 8;
    *(float4*)(kd)     = make_float4(kf[0], kf[1], kf[2], kf[3]);
    *(float4*)(kd + 4) = make_float4(kf[4], kf[5], kf[6], kf[7]);
    *(float4*)(vd)     = make_float4(vf[0], vf[1], vf[2], vf[3]);
    *(float4*)(vd + 4) = make_float4(vf[4], vf[5], vf[6], vf[7]);
  }
  __syncthreads();

  const float rscale = 0.1767766952966369f;  // 1/sqrt(32)

  for (int q0 = 0; q0 < S_; q0 += 16) {
    // ---- this wave's 4 query rows -> registers
    float qreg[4][32];
#pragma unroll
    for (int q = 0; q < 4; ++q) {
      const bf16_t* qp = Q + ((size_t)(q0 + wave * 4 + q) * B_ + b) * D_ + colbase;
#pragma unroll
      for (int e = 0; e < 4; ++e) b8f(*(const uint4*)(qp + e * 8), &qreg[q][e * 8]);
    }
    // ---- phase 1: scores (t lane-parallel: t = lane + 64j)
    float sc[4][7];
#pragma unroll
    for (int j = 0; j < 7; ++j) {
      int t = lane + 64 * j;
      const float4* krow = (const float4*)(Ks + (size_t)t * ROWK_);
      float s0 = 0.f, s1 = 0.f, s2 = 0.f, s3 = 0.f;
#pragma unroll
      for (int e = 0; e < 8; ++e) {
        float4 kv = krow[e];
        s0 += qreg[0][4 * e + 0] * kv.x; s0 += qreg[0][4 * e + 1] * kv.y;
        s0 += qreg[0][4 * e + 2] * kv.z; s0 += qreg[0][4 * e + 3] * kv.w;
        s1 += qreg[1][4 * e + 0] * kv.x; s1 += qreg[1][4 * e + 1] * kv.y;
        s1 += qreg[1][4 * e + 2] * kv.z; s1 += qreg[1][4 * e + 3] * kv.w;
        s2 += qreg[2][4 * e + 0] * kv.x; s2 += qreg[2][4 * e + 1] * kv.y;
        s2 += qreg[2][4 * e + 2] * kv.z; s2 += qreg[2][4 * e + 3] * kv.w;
        s3 += qreg[3][4 * e + 0] * kv.x; s3 += qreg[3][4 * e + 1] * kv.y;
        s3 += qreg[3][4 * e + 2] * kv.z; s3 += qreg[3][4 * e + 3] * kv.w;
      }
      sc[0][j] = s0 * rscale; sc[1][j] = s1 * rscale;
      sc[2][j] = s2 * rscale; sc[3][j] = s3 * rscale;
    }
    // softmax per query (64-lane shuffle reduce)
#pragma unroll
    for (int q = 0; q < 4; ++q) {
      float m = sc[q][0];
#pragma unroll
      for (int j = 1; j < 7; ++j) m = fmaxf(m, sc[q][j]);
#pragma unroll
      for (int o = 32; o; o >>= 1) m = fmaxf(m, __shfl_xor(m, o));
      float l = 0.f;
#pragma unroll
      for (int j = 0; j < 7; ++j) { sc[q][j] = __expf(sc[q][j] - m); l += sc[q][j]; }
#pragma unroll
      for (int o = 32; o; o >>= 1) l += __shfl_xor(l, o);
      float inv = 1.f / l;
#pragma unroll
      for (int j = 0; j < 7; ++j) sc[q][j] *= inv;
    }
    // write P[t][q16] (float4 per j)
#pragma unroll
    for (int j = 0; j < 7; ++j) {
      int t = lane + 64 * j;
      *(float4*)(Pq + (size_t)t * ROWP_ + wave * 4) =
          make_float4(sc[0][j], sc[1][j], sc[2][j], sc[3][j]);
    }
    __syncthreads();

    // ---- phase 2: ctx partials. lane = qg(2b)|d4(3b)|th(1b)
    int qg = lane >> 4;
    int d4 = (lane >> 1) & 7;
    int th = lane & 1;
    float a2[4][4];
#pragma unroll
    for (int qq = 0; qq < 4; ++qq)
#pragma unroll
      for (int i = 0; i < 4; ++i) a2[qq][i] = 0.f;
    int tbase = wave * 112 + th * 56;
    for (int t = tbase; t < tbase + 56; ++t) {
      float4 p4 = *(const float4*)(Pq + (size_t)t * ROWP_ + qg * 4);
      float4 v4 = *(const float4*)(Vs + (size_t)t * ROWV_ + d4 * 4);
      a2[0][0] += p4.x * v4.x; a2[0][1] += p4.x * v4.y;
      a2[0][2] += p4.x * v4.z; a2[0][3] += p4.x * v4.w;
      a2[1][0] += p4.y * v4.x; a2[1][1] += p4.y * v4.y;
      a2[1][2] += p4.y * v4.z; a2[1][3] += p4.y * v4.w;
      a2[2][0] += p4.z * v4.x; a2[2][1] += p4.z * v4.y;
      a2[2][2] += p4.z * v4.z; a2[2][3] += p4.z * v4.w;
      a2[3][0] += p4.w * v4.x; a2[3][1] += p4.w * v4.y;
      a2[3][2] += p4.w * v4.z; a2[3][3] += p4.w * v4.w;
    }
    __syncthreads();   // all P reads done; Pq reusable as scratch
    float* redb = Pq;  // [8 partials][16 q][32 d]
#pragma unroll
    for (int qq = 0; qq < 4; ++qq) {
      int q16 = qg * 4 + qq;
      *(float4*)(redb + ((size_t)(wave * 2 + th) * 16 + q16) * 32 + d4 * 4) =
          make_float4(a2[qq][0], a2[qq][1], a2[qq][2], a2[qq][3]);
    }
    __syncthreads();
    // reduce 8 partials -> ctx (in place over Q)
#pragma unroll
    for (int r = 0; r < 2; ++r) {
      int o = tid + r * 256;               // 0..511
      int q16 = o >> 5, dd = o & 31;
      float ssum = 0.f;
#pragma unroll
      for (int w8 = 0; w8 < 8; ++w8)
        ssum += redb[(size_t)(w8 * 16 + q16) * 32 + dd];
      Q[((size_t)(q0 + q16) * B_ + b) * D_ + colbase + dd] = f2b(ssum);
    }
    __syncthreads();   // before next iteration's P writes
  }
}

// ---------------------------------------------------------------- residual+LN
__global__ __launch_bounds__(256) void resid_ln_kernel(
    bf16_t* __restrict__ x, const bf16_t* __restrict__ y,
    const float* __restrict__ g, const float* __restrict__ be) {
  __shared__ float red[4];
  int n = blockIdx.x;
  int d = threadIdx.x;
  size_t off = (size_t)n * D_ + d;
  float v = b2f(x[off]) + b2f(y[off]);
  float sm = v;
#pragma unroll
  for (int o = 32; o; o >>= 1) sm += __shfl_xor(sm, o);
  if ((d & 63) == 0) red[d >> 6] = sm;
  __syncthreads();
  float mean = (red[0] + red[1] + red[2] + red[3]) * (1.f / 256.f);
  __syncthreads();
  float c = v - mean;
  float s2 = c * c;
#pragma unroll
  for (int o = 32; o; o >>= 1) s2 += __shfl_xor(s2, o);
  if ((d & 63) == 0) red[d >> 6] = s2;
  __syncthreads();
  float var = (red[0] + red[1] + red[2] + red[3]) * (1.f / 256.f);
  float r = rsqrtf(var + 1e-5f);
  x[off] = f2b(c * r * g[d] + be[d]);
}

// ---------------------------------------------------------------- out proj
__global__ __launch_bounds__(256) void out_kernel(
    const bf16_t* __restrict__ x, const float* __restrict__ w_out,
    const float* __restrict__ b_out, float* __restrict__ out) {
  int idx = blockIdx.x * 256 + threadIdx.x;  // (p*B+b)*F + f
  int f = idx & 7;
  int pb = idx >> 3;
  const bf16_t* xrow = x + ((size_t)(S_ - PRED_) * B_ + pb) * D_;
  float acc = b_out[f];
  for (int dd = 0; dd < D_; ++dd) acc += b2f(xrow[dd]) * w_out[dd * F_ + f];
  out[idx] = acc;
}

// ---------------------------------------------------------------- launch
extern "C" void kernel_launch(void* const* d_in, const int* in_sizes, int n_in,
                              void* d_out, int out_size, void* d_ws, size_t ws_size,
                              hipStream_t stream) {
  const float* src  = (const float*)d_in[0];
  const float* w_in = (const float*)d_in[1];
  const float* b_in = (const float*)d_in[2];
  const float* Wq = (const float*)d_in[3];
  const float* bq = (const float*)d_in[4];
  const float* Wk = (const float*)d_in[5];
  const float* bk = (const float*)d_in[6];
  const float* Wv = (const float*)d_in[7];
  const float* bv = (const float*)d_in[8];
  const float* Wo = (const float*)d_in[9];
  const float* bo = (const float*)d_in[10];
  const float* g1 = (const float*)d_in[11];
  const float* be1 = (const float*)d_in[12];
  const float* W1 = (const float*)d_in[13];
  const float* b1 = (const float*)d_in[14];
  const float* W2 = (const float*)d_in[15];
  const float* b2 = (const float*)d_in[16];
  const float* g2 = (const float*)d_in[17];
  const float* be2 = (const float*)d_in[18];
  const float* w_out = (const float*)d_in[19];
  const float* b_out = (const float*)d_in[20];
  float* out = (float*)d_out;

  // bf16 activations: 4 x 14.68 MB = 58.72 MB total workspace
  bf16_t* xb = (bf16_t*)d_ws;
  bf16_t* qb = xb + (size_t)NT_ * D_;
  bf16_t* kb = qb + (size_t)NT_ * D_;
  bf16_t* vb = kb + (size_t)NT_ * D_;

  const int ATTN_LDS = (S_ * ROWK_ + S_ * ROWV_ + S_ * ROWP_) * 4;  // 157696 B
  (void)hipFuncSetAttribute((const void*)attn_kernel,
                            hipFuncAttributeMaxDynamicSharedMemorySize, ATTN_LDS);

  embed_kernel<<<NT_, 256, 0, stream>>>(src, w_in, b_in, xb);

  for (int l = 0; l < L_; ++l) {
    const size_t woff = (size_t)l * D_ * D_;
    const size_t boff = (size_t)l * D_;
    gemm_kernel<<<dim3(224, 2), 256, 0, stream>>>(xb, Wq + woff, bq + boff, qb, 0);
    gemm_kernel<<<dim3(224, 2), 256, 0, stream>>>(xb, Wk + woff, bk + boff, kb, 0);
    gemm_kernel<<<dim3(224, 2), 256, 0, stream>>>(xb, Wv + woff, bv + boff, vb, 0);
    attn_kernel<<<512, 256, ATTN_LDS, stream>>>(qb, kb, vb);
    gemm_kernel<<<dim3(224, 2), 256, 0, stream>>>(qb, Wo + woff, bo + boff, kb, 0);
    resid_ln_kernel<<<NT_, 256, 0, stream>>>(xb, kb, g1 + boff, be1 + boff);
    gemm_kernel<<<dim3(224, 2), 256, 0, stream>>>(xb, W1 + woff, b1 + boff, qb, 1);
    gemm_kernel<<<dim3(224, 2), 256, 0, stream>>>(qb, W2 + woff, b2 + boff, kb, 0);
    resid_ln_kernel<<<NT_, 256, 0, stream>>>(xb, kb, g2 + boff, be2 + boff);
  }

  out_kernel<<<(PRED_ * B_ * F_) / 256, 256, 0, stream>>>(xb, w_out, b_out, out);
}

// Round 4
// 739.285 us; speedup vs baseline: 4.6006x; 4.6006x over previous
//
#include <hip/hip_runtime.h>
#include <math.h>

#define S_ 448
#define B_ 64
#define F_ 8
#define D_ 256
#define H_ 8
#define DK_ 32
#define L_ 4
#define PRED_ 96
#define NT_ (S_ * B_)          // 28672 tokens
#define BD_ (B_ * D_)          // 16384 row stride in token-major layout

typedef unsigned short bf16_t;
using bf16x8 = __attribute__((ext_vector_type(8))) short;   // 8 bf16 = 4 VGPR
using f32x4  = __attribute__((ext_vector_type(4))) float;   // MFMA acc

__device__ __forceinline__ float b2f(bf16_t b) {
  return __uint_as_float(((unsigned)b) << 16);
}
__device__ __forceinline__ bf16_t f2b(float f) {
  unsigned u = __float_as_uint(f);
  u += 0x7fffu + ((u >> 16) & 1u);     // round-to-nearest-even
  return (bf16_t)(u >> 16);
}
__device__ __forceinline__ void b8f(uint4 v, float* o) {
  o[0] = __uint_as_float(v.x << 16); o[1] = __uint_as_float(v.x & 0xffff0000u);
  o[2] = __uint_as_float(v.y << 16); o[3] = __uint_as_float(v.y & 0xffff0000u);
  o[4] = __uint_as_float(v.z << 16); o[5] = __uint_as_float(v.z & 0xffff0000u);
  o[6] = __uint_as_float(v.w << 16); o[7] = __uint_as_float(v.w & 0xffff0000u);
}

// ---------------------------------------------------------------- embed
__global__ __launch_bounds__(256) void embed_kernel(
    const float* __restrict__ src, const float* __restrict__ w_in,
    const float* __restrict__ b_in, bf16_t* __restrict__ x) {
  int n = blockIdx.x;          // token = s*B + b
  int d = threadIdx.x;         // 0..255
  const float* srow = src + (size_t)n * F_;
  float acc = b_in[d];
#pragma unroll
  for (int f = 0; f < F_; ++f) acc += srow[f] * w_in[f * D_ + d];
  int s = n / B_;
  int i2 = d & ~1;             // 2*i
  float freq = __expf(-9.210340371976184f * (float)i2 / (float)D_);
  float ang = (float)s * freq;
  float pe = (d & 1) ? cosf(ang) : sinf(ang);
  x[(size_t)n * D_ + d] = f2b(acc + pe);
}

// ------------------------------------------- weight transpose+convert prep
// Wt[l][n][k] (bf16) = W[l][k][n] (f32);  grid (8,8,L), block (32,8)
__global__ __launch_bounds__(256) void transpose_w_kernel(
    const float* __restrict__ W, bf16_t* __restrict__ Wt) {
  __shared__ float t[32][33];
  int l = blockIdx.z;
  int k0 = blockIdx.x * 32, n0 = blockIdx.y * 32;
  int x = threadIdx.x, y = threadIdx.y;
  const float* src = W + ((size_t)l * 256 + k0) * 256 + n0;
#pragma unroll
  for (int i = y; i < 32; i += 8) t[i][x] = src[(size_t)i * 256 + x];
  __syncthreads();
  bf16_t* dst = Wt + ((size_t)l * 256 + n0) * 256 + k0;
#pragma unroll
  for (int i = y; i < 32; i += 8) dst[(size_t)i * 256 + x] = f2b(t[x][i]);
}

// ------------------------------------------------- MFMA GEMM 128x128, BK=32
// Y[M,256](bf16) = A[M,256](bf16) @ Wt^T (Wt is [n][k] bf16) + bias, opt relu
__global__ __launch_bounds__(256, 2) void mfma_gemm_kernel(
    const bf16_t* __restrict__ A, const bf16_t* __restrict__ Wt,
    const float* __restrict__ bias, bf16_t* __restrict__ Y, int relu) {
  __shared__ bf16_t As[2][128][32];
  __shared__ bf16_t Bs[2][128][32];
  int tid = threadIdx.x, lane = tid & 63, wv = tid >> 6;
  int m0 = blockIdx.x * 128, n0 = blockIdx.y * 128;
  int wr = wv >> 1, wc = wv & 1;           // wave 64x64 sub-tile
  int jg = lane >> 4, fr = lane & 15;

  // staging coords: 2 rows-of-16 per wave per operand, slot p = lane&3
  int s_row = wv * 32 + (lane >> 2);       // + i*16
  int s_p = lane & 3;

  uint4 rA[2], rB[2];
#define STAGE_LOAD(kt)                                                        \
  {                                                                           \
    int k0 = (kt) * 32;                                                       \
    _Pragma("unroll") for (int i = 0; i < 2; ++i) {                           \
      int row = s_row + i * 16;                                               \
      int ls = s_p ^ ((row >> 1) & 3);                                        \
      rA[i] = *(const uint4*)(A + (size_t)(m0 + row) * 256 + k0 + ls * 8);    \
      rB[i] = *(const uint4*)(Wt + (size_t)(n0 + row) * 256 + k0 + ls * 8);   \
    }                                                                         \
  }
#define STAGE_WRITE(buf)                                                      \
  {                                                                           \
    _Pragma("unroll") for (int i = 0; i < 2; ++i) {                           \
      int row = s_row + i * 16;                                               \
      *(uint4*)(&As[buf][row][s_p * 8]) = rA[i];                              \
      *(uint4*)(&Bs[buf][row][s_p * 8]) = rB[i];                              \
    }                                                                         \
  }

  f32x4 zero = {0.f, 0.f, 0.f, 0.f};
  f32x4 acc[4][4];
#pragma unroll
  for (int i = 0; i < 4; ++i)
#pragma unroll
    for (int j = 0; j < 4; ++j) acc[i][j] = zero;

  STAGE_LOAD(0);
  STAGE_WRITE(0);
  __syncthreads();

  for (int kt = 0; kt < 8; ++kt) {
    int buf = kt & 1;
    if (kt < 7) STAGE_LOAD(kt + 1);
    bf16x8 af[4], bfr[4];
#pragma unroll
    for (int mi = 0; mi < 4; ++mi) {
      int row = wr * 64 + mi * 16 + fr;
      af[mi] = *(const bf16x8*)((const char*)&As[buf][0][0] + row * 64 +
                                ((jg ^ ((row >> 1) & 3)) << 4));
      int rn = wc * 64 + mi * 16 + fr;
      bfr[mi] = *(const bf16x8*)((const char*)&Bs[buf][0][0] + rn * 64 +
                                 ((jg ^ ((rn >> 1) & 3)) << 4));
    }
#pragma unroll
    for (int mi = 0; mi < 4; ++mi)
#pragma unroll
      for (int ni = 0; ni < 4; ++ni)
        acc[mi][ni] = __builtin_amdgcn_mfma_f32_16x16x32_bf16(
            af[mi], bfr[ni], acc[mi][ni], 0, 0, 0);
    if (kt < 7) {
      STAGE_WRITE((kt + 1) & 1);
      __syncthreads();
    }
  }

  // epilogue: C[row=(jg*4+r)][col=fr] per fragment
#pragma unroll
  for (int ni = 0; ni < 4; ++ni) {
    int col = n0 + wc * 64 + ni * 16 + fr;
    float bv = bias[col];
#pragma unroll
    for (int mi = 0; mi < 4; ++mi) {
      int rowb = m0 + wr * 64 + mi * 16 + jg * 4;
#pragma unroll
      for (int r = 0; r < 4; ++r) {
        float v = acc[mi][ni][r] + bv;
        if (relu) v = fmaxf(v, 0.f);
        Y[(size_t)(rowb + r) * 256 + col] = f2b(v);
      }
    }
  }
#undef STAGE_LOAD
#undef STAGE_WRITE
}

// ---------------------------------------------------------------- attention
// one block per (b,h); 4 waves, each owns 16-q tiles, 7 iterations.
__global__ __launch_bounds__(256, 2) void attn_mfma_kernel(
    bf16_t* __restrict__ Q, const bf16_t* __restrict__ K,
    const bf16_t* __restrict__ V) {
  __shared__ bf16_t Ks[448][32];     // [t][dk], slot-swizzled (28672 B)
  __shared__ bf16_t Vt[32][448];     // [dk][t], XOR-swizzled   (28672 B)
  __shared__ bf16_t Pb[4][16][32];   // per-wave P chunk        (4096 B)
  int tid = threadIdx.x, lane = tid & 63, wv = tid >> 6;
  int b = blockIdx.x >> 3, h = blockIdx.x & 7;
  const size_t base = (size_t)b * D_ + h * 32;
  int jg = lane >> 4, fr = lane & 15;

  // ---- stage K: rows wv*112 + i*16 + (lane>>2), slot p = lane&3
#pragma unroll
  for (int i = 0; i < 7; ++i) {
    int row = wv * 112 + i * 16 + (lane >> 2);
    int p = lane & 3;
    int ls = p ^ ((row >> 1) & 3);
    uint4 kv = *(const uint4*)(K + (size_t)row * BD_ + base + ls * 8);
    *(uint4*)(&Ks[row][p * 8]) = kv;
  }
  // ---- stage V transposed: Vt[dk][t], byte ^= ((dk&7)<<4)
  for (int idx = tid; idx < 448 * 4; idx += 256) {
    int t = idx >> 2, c = idx & 3;
    uint4 vv = *(const uint4*)(V + (size_t)t * BD_ + base + c * 8);
    unsigned w[4] = {vv.x, vv.y, vv.z, vv.w};
#pragma unroll
    for (int e = 0; e < 8; ++e) {
      int dk = c * 8 + e;
      bf16_t val = (bf16_t)((e & 1) ? (w[e >> 1] >> 16) : (w[e >> 1] & 0xffff));
      int byteoff = (((dk * 448 + t) << 1)) ^ ((dk & 7) << 4);
      *(bf16_t*)((char*)&Vt[0][0] + byteoff) = val;
    }
  }
  __syncthreads();

  const float sc_c = 0.25503484f;    // log2(e)/sqrt(32)
  f32x4 zero = {0.f, 0.f, 0.f, 0.f};
  char* pbase = (char*)&Pb[0][0][0] + wv * 1024;

  for (int qt = 0; qt < 7; ++qt) {
    int q0 = qt * 64 + wv * 16;
    // Q A-fragment straight from global: lane holds Q[q0+fr][jg*8..+7]
    bf16x8 qf = *(const bf16x8*)(Q + (size_t)(q0 + fr) * BD_ + base + jg * 8);

    // ---- QK^T: 28 tiles of 16 t
    f32x4 s[28];
#pragma unroll
    for (int ct = 0; ct < 28; ++ct) {
      int trow = ct * 16 + fr;
      bf16x8 kf = *(const bf16x8*)((const char*)&Ks[0][0] + trow * 64 +
                                   ((jg ^ ((trow >> 1) & 3)) << 4));
      s[ct] = __builtin_amdgcn_mfma_f32_16x16x32_bf16(qf, kf, zero, 0, 0, 0);
    }
    // lane holds S[q = jg*4+r][t = ct*16+fr]
    // ---- softmax (max over t; exp2; sum; normalization deferred to O)
    float inv[4];
#pragma unroll
    for (int r = 0; r < 4; ++r) {
      float m = s[0][r];
#pragma unroll
      for (int ct = 1; ct < 28; ++ct) m = fmaxf(m, s[ct][r]);
      m = fmaxf(m, __shfl_xor(m, 1));
      m = fmaxf(m, __shfl_xor(m, 2));
      m = fmaxf(m, __shfl_xor(m, 4));
      m = fmaxf(m, __shfl_xor(m, 8));
      float l = 0.f;
#pragma unroll
      for (int ct = 0; ct < 28; ++ct) {
        float p = exp2f((s[ct][r] - m) * sc_c);
        s[ct][r] = p;
        l += p;
      }
      l += __shfl_xor(l, 1);
      l += __shfl_xor(l, 2);
      l += __shfl_xor(l, 4);
      l += __shfl_xor(l, 8);
      inv[r] = 1.f / l;
    }
    // ---- PV: 14 chunks of 32 t
    f32x4 o[2] = {zero, zero};
#pragma unroll
    for (int c = 0; c < 14; ++c) {
      // write P chunk (bf16) into per-wave LDS, slot-swizzled rows of 64B
#pragma unroll
      for (int half = 0; half < 2; ++half)
#pragma unroll
        for (int r = 0; r < 4; ++r) {
          int q = jg * 4 + r;
          int tl = fr + 16 * half;
          int byteoff = q * 64 + ((tl ^ (((q >> 1) & 3) << 3)) << 1);
          *(bf16_t*)(pbase + byteoff) = f2b(s[2 * c + half][r]);
        }
      bf16x8 pf = *(const bf16x8*)(pbase + fr * 64 +
                                   ((jg ^ ((fr >> 1) & 3)) << 4));
#pragma unroll
      for (int nt = 0; nt < 2; ++nt) {
        int dk = nt * 16 + fr;
        int byt = (((dk * 448 + c * 32 + jg * 8) << 1)) ^ ((dk & 7) << 4);
        bf16x8 vf = *(const bf16x8*)((const char*)&Vt[0][0] + byt);
        o[nt] = __builtin_amdgcn_mfma_f32_16x16x32_bf16(pf, vf, o[nt], 0, 0, 0);
      }
    }
    // ---- scale by 1/l and store ctx in-place over Q
#pragma unroll
    for (int nt = 0; nt < 2; ++nt)
#pragma unroll
      for (int r = 0; r < 4; ++r) {
        float v = o[nt][r] * inv[r];
        Q[(size_t)(q0 + jg * 4 + r) * BD_ + base + nt * 16 + fr] = f2b(v);
      }
  }
}

// ---------------------------------------------------------------- residual+LN
// 1 token per wave, 4 tokens per block, ushort4-vectorized, no LDS.
__global__ __launch_bounds__(256) void resid_ln_kernel(
    bf16_t* __restrict__ x, const bf16_t* __restrict__ y,
    const float* __restrict__ g, const float* __restrict__ be) {
  int wv = threadIdx.x >> 6, lane = threadIdx.x & 63;
  size_t n = (size_t)blockIdx.x * 4 + wv;
  size_t off = n * D_ + lane * 4;
  ushort4 xv = *(const ushort4*)(x + off);
  ushort4 yv = *(const ushort4*)(y + off);
  float v[4];
  v[0] = b2f(xv.x) + b2f(yv.x);
  v[1] = b2f(xv.y) + b2f(yv.y);
  v[2] = b2f(xv.z) + b2f(yv.z);
  v[3] = b2f(xv.w) + b2f(yv.w);
  float sm = v[0] + v[1] + v[2] + v[3];
#pragma unroll
  for (int o = 32; o; o >>= 1) sm += __shfl_xor(sm, o);
  float mean = sm * (1.f / 256.f);
  float c[4], s2 = 0.f;
#pragma unroll
  for (int i = 0; i < 4; ++i) { c[i] = v[i] - mean; s2 += c[i] * c[i]; }
#pragma unroll
  for (int o = 32; o; o >>= 1) s2 += __shfl_xor(s2, o);
  float var = s2 * (1.f / 256.f);
  float r = rsqrtf(var + 1e-5f);
  float4 gv = *(const float4*)(g + lane * 4);
  float4 bv = *(const float4*)(be + lane * 4);
  ushort4 ov;
  ov.x = f2b(c[0] * r * gv.x + bv.x);
  ov.y = f2b(c[1] * r * gv.y + bv.y);
  ov.z = f2b(c[2] * r * gv.z + bv.z);
  ov.w = f2b(c[3] * r * gv.w + bv.w);
  *(ushort4*)(x + off) = ov;
}

// ---------------------------------------------------------------- out proj
__global__ __launch_bounds__(256) void out_kernel(
    const bf16_t* __restrict__ x, const float* __restrict__ w_out,
    const float* __restrict__ b_out, float* __restrict__ out) {
  int idx = blockIdx.x * 256 + threadIdx.x;  // (p*B+b)*F + f
  int f = idx & 7;
  int pb = idx >> 3;
  const bf16_t* xrow = x + ((size_t)(S_ - PRED_) * B_ + pb) * D_;
  float acc = b_out[f];
  for (int dd = 0; dd < D_; ++dd) acc += b2f(xrow[dd]) * w_out[dd * F_ + f];
  out[idx] = acc;
}

// ---------------------------------------------------------------- launch
extern "C" void kernel_launch(void* const* d_in, const int* in_sizes, int n_in,
                              void* d_out, int out_size, void* d_ws, size_t ws_size,
                              hipStream_t stream) {
  const float* src  = (const float*)d_in[0];
  const float* w_in = (const float*)d_in[1];
  const float* b_in = (const float*)d_in[2];
  const float* Wq = (const float*)d_in[3];
  const float* bq = (const float*)d_in[4];
  const float* Wk = (const float*)d_in[5];
  const float* bk = (const float*)d_in[6];
  const float* Wv = (const float*)d_in[7];
  const float* bv = (const float*)d_in[8];
  const float* Wo = (const float*)d_in[9];
  const float* bo = (const float*)d_in[10];
  const float* g1 = (const float*)d_in[11];
  const float* be1 = (const float*)d_in[12];
  const float* W1 = (const float*)d_in[13];
  const float* b1 = (const float*)d_in[14];
  const float* W2 = (const float*)d_in[15];
  const float* b2 = (const float*)d_in[16];
  const float* g2 = (const float*)d_in[17];
  const float* be2 = (const float*)d_in[18];
  const float* w_out = (const float*)d_in[19];
  const float* b_out = (const float*)d_in[20];
  float* out = (float*)d_out;

  const size_t NTD = (size_t)NT_ * D_;
  bf16_t* xb = (bf16_t*)d_ws;
  bf16_t* qb = xb + NTD;
  bf16_t* kb = qb + NTD;
  bf16_t* vb = kb + NTD;
  bf16_t* wt = vb + NTD;             // 6 * L * 65536 bf16 = 3.1 MB
  const size_t WSZ = (size_t)L_ * 65536;
  bf16_t* wtq = wt;
  bf16_t* wtk = wtq + WSZ;
  bf16_t* wtv = wtk + WSZ;
  bf16_t* wto = wtv + WSZ;
  bf16_t* wt1 = wto + WSZ;
  bf16_t* wt2 = wt1 + WSZ;

  dim3 tb(32, 8), tg(8, 8, L_);
  transpose_w_kernel<<<tg, tb, 0, stream>>>(Wq, wtq);
  transpose_w_kernel<<<tg, tb, 0, stream>>>(Wk, wtk);
  transpose_w_kernel<<<tg, tb, 0, stream>>>(Wv, wtv);
  transpose_w_kernel<<<tg, tb, 0, stream>>>(Wo, wto);
  transpose_w_kernel<<<tg, tb, 0, stream>>>(W1, wt1);
  transpose_w_kernel<<<tg, tb, 0, stream>>>(W2, wt2);

  embed_kernel<<<NT_, 256, 0, stream>>>(src, w_in, b_in, xb);

  dim3 gg(224, 2);
  for (int l = 0; l < L_; ++l) {
    const size_t woff = (size_t)l * 65536;
    const size_t boff = (size_t)l * D_;
    mfma_gemm_kernel<<<gg, 256, 0, stream>>>(xb, wtq + woff, bq + boff, qb, 0);
    mfma_gemm_kernel<<<gg, 256, 0, stream>>>(xb, wtk + woff, bk + boff, kb, 0);
    mfma_gemm_kernel<<<gg, 256, 0, stream>>>(xb, wtv + woff, bv + boff, vb, 0);
    attn_mfma_kernel<<<512, 256, 0, stream>>>(qb, kb, vb);
    mfma_gemm_kernel<<<gg, 256, 0, stream>>>(qb, wto + woff, bo + boff, kb, 0);
    resid_ln_kernel<<<NT_ / 4, 256, 0, stream>>>(xb, kb, g1 + boff, be1 + boff);
    mfma_gemm_kernel<<<gg, 256, 0, stream>>>(xb, wt1 + woff, b1 + boff, qb, 1);
    mfma_gemm_kernel<<<gg, 256, 0, stream>>>(qb, wt2 + woff, b2 + boff, kb, 0);
    resid_ln_kernel<<<NT_ / 4, 256, 0, stream>>>(xb, kb, g2 + boff, be2 + boff);
  }

  out_kernel<<<(PRED_ * B_ * F_) / 256, 256, 0, stream>>>(xb, w_out, b_out, out);
}

// Round 5
// 723.108 us; speedup vs baseline: 4.7036x; 1.0224x over previous
//
#include <hip/hip_runtime.h>
#include <math.h>

#define S_ 448
#define B_ 64
#define F_ 8
#define D_ 256
#define H_ 8
#define DK_ 32
#define L_ 4
#define PRED_ 96
#define NT_ (S_ * B_)          // 28672 tokens
#define PANEL_ (S_ * DK_)      // 14336 elems per (b,h) panel

typedef unsigned short bf16_t;
using bf16x8 = __attribute__((ext_vector_type(8))) short;   // 8 bf16 = 4 VGPR
using f32x4  = __attribute__((ext_vector_type(4))) float;   // MFMA acc

__device__ __forceinline__ float b2f(bf16_t b) {
  return __uint_as_float(((unsigned)b) << 16);
}
__device__ __forceinline__ bf16_t f2b(float f) {
  unsigned u = __float_as_uint(f);
  u += 0x7fffu + ((u >> 16) & 1u);     // round-to-nearest-even
  return (bf16_t)(u >> 16);
}

// ---------------------------------------------------------------- embed
__global__ __launch_bounds__(256) void embed_kernel(
    const float* __restrict__ src, const float* __restrict__ w_in,
    const float* __restrict__ b_in, bf16_t* __restrict__ x) {
  int n = blockIdx.x;          // token = s*B + b
  int d = threadIdx.x;         // 0..255
  const float* srow = src + (size_t)n * F_;
  float acc = b_in[d];
#pragma unroll
  for (int f = 0; f < F_; ++f) acc += srow[f] * w_in[f * D_ + d];
  int s = n / B_;
  int i2 = d & ~1;             // 2*i
  float freq = __expf(-9.210340371976184f * (float)i2 / (float)D_);
  float ang = (float)s * freq;
  float pe = (d & 1) ? cosf(ang) : sinf(ang);
  x[(size_t)n * D_ + d] = f2b(acc + pe);
}

// ------------------------------------------- weight transpose+convert prep
// Wt[l][n][k] (bf16) = W[l][k][n] (f32);  grid (8,8,L), block (32,8)
__global__ __launch_bounds__(256) void transpose_w_kernel(
    const float* __restrict__ W, bf16_t* __restrict__ Wt) {
  __shared__ float t[32][33];
  int l = blockIdx.z;
  int k0 = blockIdx.x * 32, n0 = blockIdx.y * 32;
  int x = threadIdx.x, y = threadIdx.y;
  const float* src = W + ((size_t)l * 256 + k0) * 256 + n0;
#pragma unroll
  for (int i = y; i < 32; i += 8) t[i][x] = src[(size_t)i * 256 + x];
  __syncthreads();
  bf16_t* dst = Wt + ((size_t)l * 256 + n0) * 256 + k0;
#pragma unroll
  for (int i = y; i < 32; i += 8) dst[(size_t)i * 256 + x] = f2b(t[x][i]);
}

// ------------------------------------------------- MFMA GEMM 128x128, BK=32
// ALAY: 0 = token-major [n][256], 1 = head-panel [(b*8+h)][s][dk]
// OLAY: same meaning for output.
template <int ALAY, int OLAY, int RELU>
__device__ __forceinline__ void gemm_body(
    const bf16_t* __restrict__ A, const bf16_t* __restrict__ Wt,
    const float* __restrict__ bias, bf16_t* __restrict__ Y, int m0, int n0) {
  __shared__ bf16_t As[2][128][32];
  __shared__ bf16_t Bs[2][128][32];
  int tid = threadIdx.x, lane = tid & 63, wv = tid >> 6;
  int wr = wv >> 1, wc = wv & 1;           // wave 64x64 sub-tile
  int jg = lane >> 4, fr = lane & 15;
  int s_row = wv * 32 + (lane >> 2);       // + i*16
  int s_p = lane & 3;

  uint4 rA[2], rB[2];

  auto stage_load = [&](int kt) {
    int k0 = kt * 32;
#pragma unroll
    for (int i = 0; i < 2; ++i) {
      int row = s_row + i * 16;
      int ls = s_p ^ ((row >> 1) & 3);
      const bf16_t* ap;
      if (ALAY == 0) {
        ap = A + (size_t)(m0 + row) * 256 + k0 + ls * 8;
      } else {
        int n = m0 + row;                  // token: s = n>>6, b = n&63
        int k = k0 + ls * 8;               // d: h = k>>5, dk = k&31
        ap = A + ((size_t)(((n & 63) << 3) | (k >> 5)) * S_ + (n >> 6)) * DK_ +
             (k & 31);
      }
      rA[i] = *(const uint4*)ap;
      rB[i] = *(const uint4*)(Wt + (size_t)(n0 + row) * 256 + k0 + ls * 8);
    }
  };
  auto stage_write = [&](int buf) {
#pragma unroll
    for (int i = 0; i < 2; ++i) {
      int row = s_row + i * 16;
      *(uint4*)(&As[buf][row][s_p * 8]) = rA[i];
      *(uint4*)(&Bs[buf][row][s_p * 8]) = rB[i];
    }
  };

  f32x4 zero = {0.f, 0.f, 0.f, 0.f};
  f32x4 acc[4][4];
#pragma unroll
  for (int i = 0; i < 4; ++i)
#pragma unroll
    for (int j = 0; j < 4; ++j) acc[i][j] = zero;

  stage_load(0);
  stage_write(0);
  __syncthreads();

  for (int kt = 0; kt < 8; ++kt) {
    int buf = kt & 1;
    if (kt < 7) stage_load(kt + 1);
    bf16x8 af[4], bfr[4];
#pragma unroll
    for (int mi = 0; mi < 4; ++mi) {
      int row = wr * 64 + mi * 16 + fr;
      af[mi] = *(const bf16x8*)((const char*)&As[buf][0][0] + row * 64 +
                                ((jg ^ ((row >> 1) & 3)) << 4));
      int rn = wc * 64 + mi * 16 + fr;
      bfr[mi] = *(const bf16x8*)((const char*)&Bs[buf][0][0] + rn * 64 +
                                 ((jg ^ ((rn >> 1) & 3)) << 4));
    }
#pragma unroll
    for (int mi = 0; mi < 4; ++mi)
#pragma unroll
      for (int ni = 0; ni < 4; ++ni)
        acc[mi][ni] = __builtin_amdgcn_mfma_f32_16x16x32_bf16(
            af[mi], bfr[ni], acc[mi][ni], 0, 0, 0);
    if (kt < 7) {
      stage_write((kt + 1) & 1);
      __syncthreads();
    }
  }

  // epilogue: C[row=(jg*4+r)][col=fr] per fragment
#pragma unroll
  for (int ni = 0; ni < 4; ++ni) {
    int col = n0 + wc * 64 + ni * 16 + fr;
    float bv = bias[col];
#pragma unroll
    for (int mi = 0; mi < 4; ++mi) {
      int rowb = m0 + wr * 64 + mi * 16 + jg * 4;
#pragma unroll
      for (int r = 0; r < 4; ++r) {
        float v = acc[mi][ni][r] + bv;
        if (RELU) v = fmaxf(v, 0.f);
        if (OLAY == 0) {
          Y[(size_t)(rowb + r) * 256 + col] = f2b(v);
        } else {
          int n = rowb + r;
          Y[((size_t)(((n & 63) << 3) | (col >> 5)) * S_ + (n >> 6)) * DK_ +
            (col & 31)] = f2b(v);
        }
      }
    }
  }
}

// fused QKV: grid (224, 6); y>>1 selects matrix, y&1 selects col-half
__global__ __launch_bounds__(256, 2) void gemm_qkv_kernel(
    const bf16_t* __restrict__ A, const bf16_t* __restrict__ wq,
    const bf16_t* __restrict__ wk, const bf16_t* __restrict__ wvp,
    const float* __restrict__ bq, const float* __restrict__ bk,
    const float* __restrict__ bvp, bf16_t* __restrict__ yq,
    bf16_t* __restrict__ yk, bf16_t* __restrict__ yv) {
  int sel = blockIdx.y >> 1;
  const bf16_t* W = sel == 0 ? wq : sel == 1 ? wk : wvp;
  const float* bb = sel == 0 ? bq : sel == 1 ? bk : bvp;
  bf16_t* Y = sel == 0 ? yq : sel == 1 ? yk : yv;
  gemm_body<0, 1, 0>(A, W, bb, Y, blockIdx.x * 128, (blockIdx.y & 1) * 128);
}

__global__ __launch_bounds__(256, 2) void gemm_ctx_kernel(
    const bf16_t* __restrict__ A, const bf16_t* __restrict__ Wt,
    const float* __restrict__ bias, bf16_t* __restrict__ Y) {
  gemm_body<1, 0, 0>(A, Wt, bias, Y, blockIdx.x * 128, blockIdx.y * 128);
}
__global__ __launch_bounds__(256, 2) void gemm_relu_kernel(
    const bf16_t* __restrict__ A, const bf16_t* __restrict__ Wt,
    const float* __restrict__ bias, bf16_t* __restrict__ Y) {
  gemm_body<0, 0, 1>(A, Wt, bias, Y, blockIdx.x * 128, blockIdx.y * 128);
}
__global__ __launch_bounds__(256, 2) void gemm_plain_kernel(
    const bf16_t* __restrict__ A, const bf16_t* __restrict__ Wt,
    const float* __restrict__ bias, bf16_t* __restrict__ Y) {
  gemm_body<0, 0, 0>(A, Wt, bias, Y, blockIdx.x * 128, blockIdx.y * 128);
}

// ---------------------------------------------------------------- attention
// one block per (b,h) panel; 4 waves, each owns 16-q tiles, 7 iterations.
__global__ __launch_bounds__(256, 2) void attn_mfma_kernel(
    bf16_t* __restrict__ Q, const bf16_t* __restrict__ K,
    const bf16_t* __restrict__ V) {
  __shared__ bf16_t Ks[448][32];     // [t][dk], slot-swizzled (28672 B)
  __shared__ bf16_t Vt[32][448];     // [dk][t], XOR-swizzled   (28672 B)
  __shared__ bf16_t Pb[4][16][32];   // per-wave P chunk        (4096 B)
  int tid = threadIdx.x, lane = tid & 63, wv = tid >> 6;
  int bh = blockIdx.x;
  bf16_t* Qp = Q + (size_t)bh * PANEL_;
  const bf16_t* Kp = K + (size_t)bh * PANEL_;
  const bf16_t* Vp = V + (size_t)bh * PANEL_;
  int jg = lane >> 4, fr = lane & 15;

  // ---- stage K: rows wv*112 + i*16 + (lane>>2), slot p = lane&3
#pragma unroll
  for (int i = 0; i < 7; ++i) {
    int row = wv * 112 + i * 16 + (lane >> 2);
    int p = lane & 3;
    int ls = p ^ ((row >> 1) & 3);
    *(uint4*)(&Ks[row][p * 8]) = *(const uint4*)(Kp + row * 32 + ls * 8);
  }
  // ---- stage V transposed: Vt[dk][t], byte ^= ((dk&7)<<4)
  for (int idx = tid; idx < 448 * 4; idx += 256) {
    int t = idx >> 2, c = idx & 3;
    uint4 vv = *(const uint4*)(Vp + t * 32 + c * 8);
    unsigned w[4] = {vv.x, vv.y, vv.z, vv.w};
#pragma unroll
    for (int e = 0; e < 8; ++e) {
      int dk = c * 8 + e;
      bf16_t val = (bf16_t)((e & 1) ? (w[e >> 1] >> 16) : (w[e >> 1] & 0xffff));
      int byteoff = (((dk * 448 + t) << 1)) ^ ((dk & 7) << 4);
      *(bf16_t*)((char*)&Vt[0][0] + byteoff) = val;
    }
  }
  __syncthreads();

  const float sc_c = 0.25503484f;    // log2(e)/sqrt(32)
  f32x4 zero = {0.f, 0.f, 0.f, 0.f};
  char* pbase = (char*)&Pb[0][0][0] + wv * 1024;

  for (int qt = 0; qt < 7; ++qt) {
    int q0 = qt * 64 + wv * 16;
    // Q A-fragment straight from global: lane holds Q[q0+fr][jg*8..+7]
    bf16x8 qf = *(const bf16x8*)(Qp + (q0 + fr) * 32 + jg * 8);

    // ---- QK^T: 28 tiles of 16 t
    f32x4 s[28];
#pragma unroll
    for (int ct = 0; ct < 28; ++ct) {
      int trow = ct * 16 + fr;
      bf16x8 kf = *(const bf16x8*)((const char*)&Ks[0][0] + trow * 64 +
                                   ((jg ^ ((trow >> 1) & 3)) << 4));
      s[ct] = __builtin_amdgcn_mfma_f32_16x16x32_bf16(qf, kf, zero, 0, 0, 0);
    }
    // lane holds S[q = jg*4+r][t = ct*16+fr]
    // ---- softmax (max over t; exp2; sum; normalization deferred to O)
    float inv[4];
#pragma unroll
    for (int r = 0; r < 4; ++r) {
      float m = s[0][r];
#pragma unroll
      for (int ct = 1; ct < 28; ++ct) m = fmaxf(m, s[ct][r]);
      m = fmaxf(m, __shfl_xor(m, 1));
      m = fmaxf(m, __shfl_xor(m, 2));
      m = fmaxf(m, __shfl_xor(m, 4));
      m = fmaxf(m, __shfl_xor(m, 8));
      float l = 0.f;
#pragma unroll
      for (int ct = 0; ct < 28; ++ct) {
        float p = exp2f((s[ct][r] - m) * sc_c);
        s[ct][r] = p;
        l += p;
      }
      l += __shfl_xor(l, 1);
      l += __shfl_xor(l, 2);
      l += __shfl_xor(l, 4);
      l += __shfl_xor(l, 8);
      inv[r] = 1.f / l;
    }
    // ---- PV: 14 chunks of 32 t
    f32x4 o[2] = {zero, zero};
#pragma unroll
    for (int c = 0; c < 14; ++c) {
      // write P chunk (bf16) into per-wave LDS, slot-swizzled rows of 64B
#pragma unroll
      for (int half = 0; half < 2; ++half)
#pragma unroll
        for (int r = 0; r < 4; ++r) {
          int q = jg * 4 + r;
          int tl = fr + 16 * half;
          int byteoff = q * 64 + ((tl ^ (((q >> 1) & 3) << 3)) << 1);
          *(bf16_t*)(pbase + byteoff) = f2b(s[2 * c + half][r]);
        }
      bf16x8 pf = *(const bf16x8*)(pbase + fr * 64 +
                                   ((jg ^ ((fr >> 1) & 3)) << 4));
#pragma unroll
      for (int nt = 0; nt < 2; ++nt) {
        int dk = nt * 16 + fr;
        int byt = (((dk * 448 + c * 32 + jg * 8) << 1)) ^ ((dk & 7) << 4);
        bf16x8 vf = *(const bf16x8*)((const char*)&Vt[0][0] + byt);
        o[nt] = __builtin_amdgcn_mfma_f32_16x16x32_bf16(pf, vf, o[nt], 0, 0, 0);
      }
    }
    // ---- scale by 1/l and store ctx in-place over Q (panel layout)
#pragma unroll
    for (int nt = 0; nt < 2; ++nt)
#pragma unroll
      for (int r = 0; r < 4; ++r) {
        float v = o[nt][r] * inv[r];
        Qp[(q0 + jg * 4 + r) * 32 + nt * 16 + fr] = f2b(v);
      }
  }
}

// ---------------------------------------------------------------- residual+LN
// 1 token per wave, 4 tokens per block, ushort4-vectorized, no LDS.
__global__ __launch_bounds__(256) void resid_ln_kernel(
    bf16_t* __restrict__ x, const bf16_t* __restrict__ y,
    const float* __restrict__ g, const float* __restrict__ be) {
  int wv = threadIdx.x >> 6, lane = threadIdx.x & 63;
  size_t n = (size_t)blockIdx.x * 4 + wv;
  size_t off = n * D_ + lane * 4;
  ushort4 xv = *(const ushort4*)(x + off);
  ushort4 yv = *(const ushort4*)(y + off);
  float v[4];
  v[0] = b2f(xv.x) + b2f(yv.x);
  v[1] = b2f(xv.y) + b2f(yv.y);
  v[2] = b2f(xv.z) + b2f(yv.z);
  v[3] = b2f(xv.w) + b2f(yv.w);
  float sm = v[0] + v[1] + v[2] + v[3];
#pragma unroll
  for (int o = 32; o; o >>= 1) sm += __shfl_xor(sm, o);
  float mean = sm * (1.f / 256.f);
  float c[4], s2 = 0.f;
#pragma unroll
  for (int i = 0; i < 4; ++i) { c[i] = v[i] - mean; s2 += c[i] * c[i]; }
#pragma unroll
  for (int o = 32; o; o >>= 1) s2 += __shfl_xor(s2, o);
  float var = s2 * (1.f / 256.f);
  float r = rsqrtf(var + 1e-5f);
  float4 gv = *(const float4*)(g + lane * 4);
  float4 bv = *(const float4*)(be + lane * 4);
  ushort4 ov;
  ov.x = f2b(c[0] * r * gv.x + bv.x);
  ov.y = f2b(c[1] * r * gv.y + bv.y);
  ov.z = f2b(c[2] * r * gv.z + bv.z);
  ov.w = f2b(c[3] * r * gv.w + bv.w);
  *(ushort4*)(x + off) = ov;
}

// ---------------------------------------------------------------- out proj
__global__ __launch_bounds__(256) void out_kernel(
    const bf16_t* __restrict__ x, const float* __restrict__ w_out,
    const float* __restrict__ b_out, float* __restrict__ out) {
  int idx = blockIdx.x * 256 + threadIdx.x;  // (p*B+b)*F + f
  int f = idx & 7;
  int pb = idx >> 3;
  const bf16_t* xrow = x + ((size_t)(S_ - PRED_) * B_ + pb) * D_;
  float acc = b_out[f];
  for (int dd = 0; dd < D_; ++dd) acc += b2f(xrow[dd]) * w_out[dd * F_ + f];
  out[idx] = acc;
}

// ---------------------------------------------------------------- launch
extern "C" void kernel_launch(void* const* d_in, const int* in_sizes, int n_in,
                              void* d_out, int out_size, void* d_ws, size_t ws_size,
                              hipStream_t stream) {
  const float* src  = (const float*)d_in[0];
  const float* w_in = (const float*)d_in[1];
  const float* b_in = (const float*)d_in[2];
  const float* Wq = (const float*)d_in[3];
  const float* bq = (const float*)d_in[4];
  const float* Wk = (const float*)d_in[5];
  const float* bk = (const float*)d_in[6];
  const float* Wv = (const float*)d_in[7];
  const float* bv = (const float*)d_in[8];
  const float* Wo = (const float*)d_in[9];
  const float* bo = (const float*)d_in[10];
  const float* g1 = (const float*)d_in[11];
  const float* be1 = (const float*)d_in[12];
  const float* W1 = (const float*)d_in[13];
  const float* b1 = (const float*)d_in[14];
  const float* W2 = (const float*)d_in[15];
  const float* b2 = (const float*)d_in[16];
  const float* g2 = (const float*)d_in[17];
  const float* be2 = (const float*)d_in[18];
  const float* w_out = (const float*)d_in[19];
  const float* b_out = (const float*)d_in[20];
  float* out = (float*)d_out;

  const size_t NTD = (size_t)NT_ * D_;
  bf16_t* xb = (bf16_t*)d_ws;        // token-major [n][256]
  bf16_t* qb = xb + NTD;             // panel [(b,h)][448][32] (or tok-major)
  bf16_t* kb = qb + NTD;
  bf16_t* vb = kb + NTD;
  bf16_t* wt = vb + NTD;             // 6 * L * 65536 bf16 = 3.1 MB
  const size_t WSZ = (size_t)L_ * 65536;
  bf16_t* wtq = wt;
  bf16_t* wtk = wtq + WSZ;
  bf16_t* wtv = wtk + WSZ;
  bf16_t* wto = wtv + WSZ;
  bf16_t* wt1 = wto + WSZ;
  bf16_t* wt2 = wt1 + WSZ;

  dim3 tb(32, 8), tg(8, 8, L_);
  transpose_w_kernel<<<tg, tb, 0, stream>>>(Wq, wtq);
  transpose_w_kernel<<<tg, tb, 0, stream>>>(Wk, wtk);
  transpose_w_kernel<<<tg, tb, 0, stream>>>(Wv, wtv);
  transpose_w_kernel<<<tg, tb, 0, stream>>>(Wo, wto);
  transpose_w_kernel<<<tg, tb, 0, stream>>>(W1, wt1);
  transpose_w_kernel<<<tg, tb, 0, stream>>>(W2, wt2);

  embed_kernel<<<NT_, 256, 0, stream>>>(src, w_in, b_in, xb);

  dim3 gg(224, 2);
  for (int l = 0; l < L_; ++l) {
    const size_t woff = (size_t)l * 65536;
    const size_t boff = (size_t)l * D_;
    gemm_qkv_kernel<<<dim3(224, 6), 256, 0, stream>>>(
        xb, wtq + woff, wtk + woff, wtv + woff, bq + boff, bk + boff,
        bv + boff, qb, kb, vb);
    attn_mfma_kernel<<<512, 256, 0, stream>>>(qb, kb, vb);
    gemm_ctx_kernel<<<gg, 256, 0, stream>>>(qb, wto + woff, bo + boff, kb);
    resid_ln_kernel<<<NT_ / 4, 256, 0, stream>>>(xb, kb, g1 + boff, be1 + boff);
    gemm_relu_kernel<<<gg, 256, 0, stream>>>(xb, wt1 + woff, b1 + boff, qb);
    gemm_plain_kernel<<<gg, 256, 0, stream>>>(qb, wt2 + woff, b2 + boff, kb);
    resid_ln_kernel<<<NT_ / 4, 256, 0, stream>>>(xb, kb, g2 + boff, be2 + boff);
  }

  out_kernel<<<(PRED_ * B_ * F_) / 256, 256, 0, stream>>>(xb, w_out, b_out, out);
}